// Round 12
// baseline (100.366 us; speedup 1.0000x reference)
//
#include <hip/hip_runtime.h>
#include <math.h>

// Problem constants
#define BB 16
#define TT 2048
#define CC 512
#define GG 2
#define DD 256      // C/G
#define VV 320
#define DT (DD*TT)
#define NOUT ((size_t)BB*TT*CC)

// Workspace layout (bytes)
#define OFF_H      0ULL
#define SZ_H       ((size_t)BB*GG*TT*DD*4)          // 67108864
#define OFF_PART   (OFF_H + SZ_H)
#define OFF_MUSIG  (OFF_PART + 4096ULL*2*8)
#define OFF_ESQ    (OFF_MUSIG + 32ULL*2*4)
#define OFF_CNT    (OFF_ESQ + (size_t)GG*VV*4)
#define OFF_LOSS   (OFF_CNT + (size_t)GG*VV*4)
#define OFF_EMBH   67180032ULL                       // G*8*4*320*8 halfs = 327680 B
#define OFF_WH     (OFF_EMBH + 327680ULL)            // G*8*4*256*8 halfs = 262144 B
#define OFF_WL     (OFF_WH + 262144ULL)

typedef _Float16 half8   __attribute__((ext_vector_type(8)));
typedef float    f32x4   __attribute__((ext_vector_type(4)));

#define MARGIN 2e-3f
#define CAP 16

#define GLOAD_LDS16(g, l) \
  __builtin_amdgcn_global_load_lds((const __attribute__((address_space(1))) void*)(g), \
                                   (__attribute__((address_space(3))) void*)(l), 16, 0, 0)

// blocks 0..39: esq + emb fp16-hi plane. block 40: init. blocks 41..56: W hi/lo planes.
__global__ __launch_bounds__(256) void k_emb(const float* __restrict__ emb,
                                             const float* __restrict__ w,
                                             _Float16* __restrict__ embHp,
                                             _Float16* __restrict__ wHp,
                                             _Float16* __restrict__ wLp,
                                             float* __restrict__ esq,
                                             unsigned* __restrict__ counts,
                                             float* __restrict__ loss) {
  int blk = blockIdx.x;
  int tid = threadIdx.x;
  if (blk == 40) {
    for (int i = tid; i < GG*VV; i += 256) counts[i] = 0u;
    if (tid == 0) *loss = 0.0f;
    return;
  }
  if (blk >= 41) {
    int wblk = blk - 41;
    int g = wblk >> 3, c = wblk & 7;
    int o = tid;
    const float* wrow = w + (size_t)(g*DD + o)*DD + (c << 5);
    #pragma unroll
    for (int hgrp = 0; hgrp < 4; ++hgrp) {
      float4 f1 = *(const float4*)(wrow + (hgrp << 2));
      float4 f2 = *(const float4*)(wrow + (hgrp << 2) + 16);
      float fv[8] = {f1.x, f1.y, f1.z, f1.w, f2.x, f2.y, f2.z, f2.w};
      half8 vh, vl;
      #pragma unroll
      for (int e = 0; e < 8; ++e) {
        _Float16 hh = (_Float16)fv[e];
        vh[e] = hh;
        vl[e] = (_Float16)(fv[e] - (float)hh);
      }
      size_t base = (((((size_t)(g*8 + c)) << 2) + hgrp) << 8) + o;
      *(half8*)(wHp + (base << 3)) = vh;
      *(half8*)(wLp + (base << 3)) = vl;
    }
    return;
  }
  int g = blk / 20;
  int v0 = (blk % 20) * 16;
  int vl = tid >> 4, dl = tid & 15;
  int v = v0 + vl;
  double sq = 0.0;
  #pragma unroll
  for (int k = 0; k < 16; k++) {
    int d = dl + (k << 4);
    float e = emb[((size_t)v*GG + g)*DD + d];
    sq += (double)e * (double)e;
  }
  #pragma unroll
  for (int m = 1; m < 16; m <<= 1) sq += __shfl_xor(sq, m);
  if (dl == 0) esq[g*VV + v] = (float)sq;

  const int hgrp = dl >> 2, jb = dl & 3;
  #pragma unroll
  for (int c = 0; c < 8; ++c) {
    int k0 = (c << 5) + (hgrp << 2) + jb;
    int k1 = k0 + 16;
    float e0 = emb[((size_t)v*GG + g)*DD + k0];
    float e1 = emb[((size_t)v*GG + g)*DD + k1];
    size_t base = (((size_t)(g*8 + c)*4 + hgrp)*320 + v)*8;
    embHp[base + jb]     = (_Float16)e0;
    embHp[base + jb + 4] = (_Float16)e1;
  }
}

// Conv GEMM, fp16-split 3-pass (bit-identical math): counted-vmcnt pipeline.
__global__ __launch_bounds__(256, 2) void k_conv2(const float* __restrict__ x,
                                                  const _Float16* __restrict__ wH,
                                                  const _Float16* __restrict__ wL,
                                                  float* __restrict__ h,
                                                  double* __restrict__ part) {
  __shared__ __align__(16) char BsC[65536];
  __shared__ double r1[4], r2[4];
  const int bid = blockIdx.x;         // 512
  const int bg = bid >> 4, tt = bid & 15;
  const int b = bg >> 1, g = bg & 1;
  const int tid = threadIdx.x;
  const int wv = tid >> 6, lane = tid & 63;
  const int l15 = tid & 15, lh = lane >> 4;
  const int t0w = (tt << 7) + (wv << 5);

  f32x4 acc[2][16];
  #pragma unroll
  for (int tf = 0; tf < 2; ++tf)
    #pragma unroll
    for (int vf = 0; vf < 16; ++vf) acc[tf][vf] = 0.0f;

  const char* WHg = (const char*)(wH + ((size_t)g << 16));
  const char* WLg = (const char*)(wL + ((size_t)g << 16));
  const float* xb0 = x + ((size_t)(b*TT + t0w + l15)*CC + g*DD + (lh << 2));
  const float* xb1 = xb0 + ((size_t)16)*CC;

  {
    const char* sH = WHg + wv*4096 + lane*16;
    const char* sL = WLg + wv*4096 + lane*16;
    char* dH = BsC + wv*4096;
    char* dL = BsC + 32768 + wv*4096;
    #pragma unroll
    for (int i = 0; i < 4; ++i) {
      GLOAD_LDS16(sH + i*1024, dH + i*1024);
      GLOAD_LDS16(sL + i*1024, dL + i*1024);
    }
  }
  float4 p00 = *(const float4*)(xb0);
  float4 p01 = *(const float4*)(xb0 + 16);
  float4 p10 = *(const float4*)(xb1);
  float4 p11 = *(const float4*)(xb1 + 16);

  int cur = 0;
  #pragma unroll 1
  for (int c = 0; c < 8; ++c) {
    if (c < 7) {
      const char* sH = WHg + (size_t)(c + 1)*16384 + wv*4096 + lane*16;
      const char* sL = WLg + (size_t)(c + 1)*16384 + wv*4096 + lane*16;
      char* dH = BsC + (cur ^ 1)*16384 + wv*4096;
      char* dL = BsC + 32768 + (cur ^ 1)*16384 + wv*4096;
      #pragma unroll
      for (int i = 0; i < 4; ++i) {
        GLOAD_LDS16(sH + i*1024, dH + i*1024);
        GLOAD_LDS16(sL + i*1024, dL + i*1024);
      }
      asm volatile("s_waitcnt vmcnt(12)" ::: "memory");
    } else {
      asm volatile("s_waitcnt vmcnt(4)" ::: "memory");
    }
    __builtin_amdgcn_s_barrier();

    float4 c00 = p00, c01 = p01, c10 = p10, c11 = p11;
    if (c < 7) {
      const int off = (c + 1) << 5;
      p00 = *(const float4*)(xb0 + off);
      p01 = *(const float4*)(xb0 + off + 16);
      p10 = *(const float4*)(xb1 + off);
      p11 = *(const float4*)(xb1 + off + 16);
    }
    half8 ah[2], al[2];
    {
      float fv0[8] = {c00.x, c00.y, c00.z, c00.w, c01.x, c01.y, c01.z, c01.w};
      float fv1[8] = {c10.x, c10.y, c10.z, c10.w, c11.x, c11.y, c11.z, c11.w};
      #pragma unroll
      for (int e = 0; e < 8; ++e) {
        _Float16 h0 = (_Float16)fv0[e];
        ah[0][e] = h0; al[0][e] = (_Float16)(fv0[e] - (float)h0);
        _Float16 h1 = (_Float16)fv1[e];
        ah[1][e] = h1; al[1][e] = (_Float16)(fv1[e] - (float)h1);
      }
    }
    const char* BH = BsC + cur*16384;
    const char* BL = BsC + 32768 + cur*16384;
    #pragma unroll
    for (int vf = 0; vf < 16; ++vf) {
      const int o = (vf << 4) + l15;
      const int bo = ((lh << 8) + o) << 4;
      half8 bh = *(const half8*)(BH + bo);
      half8 bl = *(const half8*)(BL + bo);
      #pragma unroll
      for (int tf = 0; tf < 2; ++tf) {
        acc[tf][vf] = __builtin_amdgcn_mfma_f32_16x16x32_f16(ah[tf], bh, acc[tf][vf], 0, 0, 0);
        acc[tf][vf] = __builtin_amdgcn_mfma_f32_16x16x32_f16(al[tf], bh, acc[tf][vf], 0, 0, 0);
        acc[tf][vf] = __builtin_amdgcn_mfma_f32_16x16x32_f16(ah[tf], bl, acc[tf][vf], 0, 0, 0);
      }
    }
    __builtin_amdgcn_s_barrier();
    cur ^= 1;
  }

  double s1 = 0.0, s2 = 0.0;
  {
    float* hb = h + (size_t)bg*TT*DD;
    #pragma unroll
    for (int tf = 0; tf < 2; ++tf) {
      #pragma unroll
      for (int reg = 0; reg < 4; ++reg) {
        const int t = t0w + (tf << 4) + (lh << 2) + reg;
        float* hrow = hb + (size_t)t*DD + l15;
        #pragma unroll
        for (int vf = 0; vf < 16; ++vf) {
          float v = acc[tf][vf][reg];
          hrow[vf << 4] = v;
          double dv = (double)v;
          s1 += dv; s2 += dv*dv;
        }
      }
    }
  }
  #pragma unroll
  for (int m = 32; m > 0; m >>= 1) { s1 += __shfl_down(s1, m); s2 += __shfl_down(s2, m); }
  if (lane == 0) { r1[wv] = s1; r2[wv] = s2; }
  __syncthreads();
  if (tid == 0) {
    part[(size_t)bid*2]     = r1[0] + r1[1] + r1[2] + r1[3];
    part[(size_t)bid*2 + 1] = r2[0] + r2[1] + r2[2] + r2[3];
  }
}

// MFMA VQ: R11 structure + per-block K-chunk ROTATION (cst = bid&7) to break
// the cross-block L2 same-line hotspot. All else identical to R11.
__global__ __launch_bounds__(256, 3) void k_vq2(const float* __restrict__ h,
                                                const double* __restrict__ part,
                                                const float* __restrict__ gn_w,
                                                const float* __restrict__ gn_b,
                                                const _Float16* __restrict__ embH,
                                                const float* __restrict__ esq,
                                                const float* __restrict__ emb,
                                                float* __restrict__ out,
                                                unsigned* __restrict__ counts,
                                                float* __restrict__ loss) {
  __shared__ __align__(16) char smem[43008];   // B dbuf 2x20480 | gnws 1K | gnbs 1K
  float*  esqs    = (float*)smem;                // overlay (after K-loop): 320 f
  int*    candcnt = (int*)(smem + 1280);         // 64
  int*    bestv   = (int*)(smem + 1536);         // 64
  int*    slowl   = (int*)(smem + 1792);         // 64
  int*    nslow   = (int*)(smem + 2048);
  float*  ze2s    = (float*)(smem + 2112);       // 64
  float*  ymins   = (float*)(smem + 2368);       // 64
  float*  lossrow = (float*)(smem + 2624);       // 64
  unsigned short* cand = (unsigned short*)(smem + 2880);  // [64][CAP]
  float*  gnws    = (float*)(smem + 40960);      // 256 f (outside dbuf + overlay)
  float*  gnbs    = (float*)(smem + 41984);      // 256 f

  const int bid = blockIdx.x;        // 1024 blocks, natural order
  const int bg  = bid >> 5;
  const int t0  = (bid & 31) << 6;
  const int b = bg >> 1, g = bg & 1;
  const int cst = bid & 7;           // chunk rotation phase
  const int tid = threadIdx.x;
  const int lane = tid & 63, wv = tid >> 6;
  const int l15 = tid & 15, lh = lane >> 4;

  // mu/rs: redundant per-thread double sum over part (bit-identical to k_stats)
  float mu, rs;
  {
    double s1 = 0.0, s2 = 0.0;
    const double* pp = part + (size_t)bg*32;
    for (int r = 0; r < 16; r++) { s1 += pp[r*2]; s2 += pp[r*2 + 1]; }
    double mud = s1 / (double)DT;
    double var = s2 / (double)DT - mud*mud;
    double rsd = 1.0 / sqrt(var + 1e-5);
    mu = (float)mud;
    rs = (float)rsd;
  }

  const float* hb = h + ((size_t)bg*TT + t0)*DD;
  const char* gBH = (const char*)(embH + (size_t)(g*8)*10240);
  const float* gwp = gn_w + g*DD;
  const float* gbp = gn_b + g*DD;

  // hoist gn into LDS once
  gnws[tid] = gwp[tid];
  gnbs[tid] = gbp[tid];
  __syncthreads();

  f32x4 acc[20];
  #pragma unroll
  for (int vf = 0; vf < 20; ++vf) acc[vf] = 0.0f;

  const float* hb0 = hb + (size_t)((wv << 4) + l15)*DD + (lh << 2);

  // prologue (rotated): h chunk cst (2), h chunk cst+1 (2), stage B chunk cst (5)
  float4 a00 = *(const float4*)(hb0 + (cst << 5));
  float4 a01 = *(const float4*)(hb0 + (cst << 5) + 16);
  float4 n00 = *(const float4*)(hb0 + (((cst + 1) & 7) << 5));
  float4 n01 = *(const float4*)(hb0 + (((cst + 1) & 7) << 5) + 16);
  asm volatile("" ::: "memory");
  {
    const char* sB = gBH + (size_t)cst*20480 + wv*5120 + lane*16;
    char* dB = smem + wv*5120;
    #pragma unroll
    for (int i = 0; i < 5; ++i) GLOAD_LDS16(sB + i*1024, dB + i*1024);
  }

  float ze2acc = 0.0f;
  #pragma unroll
  for (int c = 0; c < 8; ++c) {
    const int cu = c & 1;
    const int cc = (c + cst) & 7;        // actual chunk this iteration
    // stage B chunk cc+1 into other buffer
    if (c < 7) {
      const char* sB = gBH + (size_t)((cc + 1) & 7)*20480 + wv*5120 + lane*16;
      char* dB = smem + (cu ^ 1)*20480 + wv*5120;
      #pragma unroll
      for (int i = 0; i < 5; ++i) GLOAD_LDS16(sB + i*1024, dB + i*1024);
    }
    asm volatile("" ::: "memory");
    // issue h chunk cc+2 (depth-2 prefetch)
    float4 f00 = a00, f01 = a01;
    if (c < 6) {
      const int off = (((cc + 2) & 7)) << 5;
      f00 = *(const float4*)(hb0 + off);
      f01 = *(const float4*)(hb0 + off + 16);
    }
    // counted drain of stage_c (queue audited in R11; rotation changes only addresses)
    if (c == 7)                 { asm volatile("s_waitcnt vmcnt(0)" ::: "memory"); }
    else if (c == 0 || c == 6)  { asm volatile("s_waitcnt vmcnt(7)" ::: "memory"); }
    else                        { asm volatile("s_waitcnt vmcnt(9)" ::: "memory"); }
    __builtin_amdgcn_s_barrier();

    const int c32 = cc << 5;
    half8 ah;
    {
      float4 w1 = *(const float4*)(gnws + c32 + (lh << 2));
      float4 w2 = *(const float4*)(gnws + c32 + (lh << 2) + 16);
      float4 b1 = *(const float4*)(gnbs + c32 + (lh << 2));
      float4 b2 = *(const float4*)(gnbs + c32 + (lh << 2) + 16);
      float fv[8]  = {a00.x, a00.y, a00.z, a00.w, a01.x, a01.y, a01.z, a01.w};
      float wv_[8] = {w1.x, w1.y, w1.z, w1.w, w2.x, w2.y, w2.z, w2.w};
      float bv_[8] = {b1.x, b1.y, b1.z, b1.w, b2.x, b2.y, b2.z, b2.w};
      #pragma unroll
      for (int e = 0; e < 8; ++e) {
        float z = __fmul_rn(__fsub_rn(fv[e], mu), rs);
        z = __fadd_rn(__fmul_rn(z, wv_[e]), bv_[e]);
        ah[e] = (_Float16)z;
        ze2acc = fmaf(z, z, ze2acc);
      }
    }
    const char* BH = smem + cu*20480;
    #pragma unroll
    for (int vf = 0; vf < 20; ++vf) {
      const int v = (vf << 4) + l15;
      half8 bh = *(const half8*)(BH + ((lh*320 + v) << 4));
      acc[vf] = __builtin_amdgcn_mfma_f32_16x16x32_f16(ah, bh, acc[vf], 0, 0, 0);
    }
    __builtin_amdgcn_s_barrier();
    // rotate A registers
    a00 = n00; a01 = n01; n00 = f00; n01 = f01;
  }
  __syncthreads();

  // ---- epilogue: overlay init + ze2 ----
  if (tid < 160) { esqs[tid] = esq[g*VV + tid]; esqs[tid + 160] = esq[g*VV + tid + 160]; }
  if (tid < 64) { candcnt[tid] = 0; bestv[tid] = -1; }
  if (tid == 0) *nslow = 0;
  {
    float s = ze2acc;
    s += __shfl_down(s, 32);
    s += __shfl_down(s, 16);
    if (lane < 16) ze2s[(wv << 4) + l15] = s;
  }
  __syncthreads();

  // selection: y = esq - 2c'; candidates within MARGIN of row min
  #pragma unroll
  for (int reg = 0; reg < 4; ++reg) {
    int row = (wv << 4) + (lh << 2) + reg;
    float y[20]; float mn = 3.4e38f;
    #pragma unroll
    for (int vf = 0; vf < 20; ++vf) {
      y[vf] = fmaf(-2.0f, acc[vf][reg], esqs[(vf << 4) + l15]);
      mn = fminf(mn, y[vf]);
    }
    #pragma unroll
    for (int m = 1; m < 16; m <<= 1) mn = fminf(mn, __shfl_xor(mn, m));
    if (l15 == 0) ymins[row] = mn;
    float thr = mn + MARGIN;
    #pragma unroll
    for (int vf = 0; vf < 20; ++vf) {
      if (y[vf] <= thr) {
        int pos = atomicAdd(&candcnt[row], 1);
        if (pos < CAP) cand[row*CAP + pos] = (unsigned short)((vf << 4) + l15);
      }
    }
  }
  __syncthreads();
  if (tid < 64) {
    int cnt = candcnt[tid];
    if (cnt == 1) {
      bestv[tid] = cand[tid*CAP];
      lossrow[tid] = ze2s[tid] + ymins[tid];
    } else {
      int p = atomicAdd(nslow, 1); slowl[p] = tid;
    }
  }
  __syncthreads();

  // slow path: wave-parallel double-precision recheck
  const int ns = *nslow;
  for (int i = wv; i < ns; i += 4) {
    const int row = slowl[i];
    float4 hx  = *(const float4*)(hb + (size_t)row*DD + (lane << 2));
    float4 gw4 = *(const float4*)(gwp + (lane << 2));
    float4 gb4 = *(const float4*)(gbp + (lane << 2));
    float hv[4] = {hx.x, hx.y, hx.z, hx.w};
    float gwv[4] = {gw4.x, gw4.y, gw4.z, gw4.w};
    float gbv[4] = {gb4.x, gb4.y, gb4.z, gb4.w};
    float zf[4];
    #pragma unroll
    for (int e = 0; e < 4; ++e) {
      float z = __fmul_rn(__fsub_rn(hv[e], mu), rs);
      zf[e] = __fadd_rn(__fmul_rn(z, gwv[e]), gbv[e]);
    }
    int cnt = candcnt[row];
    double bd = 1e300; int bvv = 0x7fffffff;
    if (cnt <= CAP) {
      for (int ci = 0; ci < cnt; ++ci) {
        int v = cand[row*CAP + ci];
        float4 ev = *(const float4*)(emb + ((size_t)v*GG + g)*DD + (lane << 2));
        float evv[4] = {ev.x, ev.y, ev.z, ev.w};
        double s = 0.0;
        #pragma unroll
        for (int e = 0; e < 4; ++e) {
          double df = (double)zf[e] - (double)evv[e];
          s += df*df;
        }
        #pragma unroll
        for (int m = 32; m > 0; m >>= 1) s += __shfl_down(s, m);
        s = __shfl(s, 0);
        if (s < bd || (s == bd && v < bvv)) { bd = s; bvv = v; }
      }
    } else {
      for (int v = 0; v < VV; ++v) {
        float4 ev = *(const float4*)(emb + ((size_t)v*GG + g)*DD + (lane << 2));
        float evv[4] = {ev.x, ev.y, ev.z, ev.w};
        double s = 0.0;
        #pragma unroll
        for (int e = 0; e < 4; ++e) {
          double df = (double)zf[e] - (double)evv[e];
          s += df*df;
        }
        #pragma unroll
        for (int m = 32; m > 0; m >>= 1) s += __shfl_down(s, m);
        s = __shfl(s, 0);
        if (s < bd) { bd = s; bvv = v; }
      }
    }
    if (lane == 0) { bestv[row] = bvv; lossrow[row] = (float)bd; }
  }
  __syncthreads();

  if (tid < 64) atomicAdd(&counts[g*VV + bestv[tid]], 1u);
  if (wv == 0) {
    float s = lossrow[lane];
    #pragma unroll
    for (int m = 32; m > 0; m >>= 1) s += __shfl_down(s, m);
    if (lane == 0) atomicAdd(loss, s);
  }

  // Phase 3: x_out = selected embedding, 8-row batches for ILP
  float* ob = out + (size_t)(b*TT + t0)*CC + g*DD + tid;
  #pragma unroll 1
  for (int r0 = 0; r0 < 64; r0 += 8) {
    int vv[8]; float ee[8];
    #pragma unroll
    for (int j = 0; j < 8; ++j) vv[j] = bestv[r0 + j];
    #pragma unroll
    for (int j = 0; j < 8; ++j) ee[j] = emb[((size_t)vv[j]*GG + g)*DD + tid];
    #pragma unroll
    for (int j = 0; j < 8; ++j) ob[(size_t)(r0 + j)*CC] = ee[j];
  }
}

__global__ __launch_bounds__(256) void k_final(const unsigned* __restrict__ counts,
                                               const float* __restrict__ loss,
                                               float* __restrict__ out) {
  __shared__ float sd[256];
  int tid = threadIdx.x;
  float perp = 0.0f;
  for (int g = 0; g < GG; g++) {
    float p1 = 0.0f;
    for (int v = tid; v < VV; v += 256) {
      float p = (float)counts[g*VV + v] / 32768.0f;
      p1 += p * logf(p + 1e-7f);
    }
    sd[tid] = p1;
    __syncthreads();
    for (int s = 128; s > 0; s >>= 1) {
      if (tid < s) sd[tid] += sd[tid + s];
      __syncthreads();
    }
    if (tid == 0) perp += expf(-sd[0]);
    __syncthreads();
  }
  if (tid == 0) {
    out[NOUT]     = 1.25f * (*loss) / (float)NOUT;
    out[NOUT + 1] = perp;
  }
}

extern "C" void kernel_launch(void* const* d_in, const int* in_sizes, int n_in,
                              void* d_out, int out_size, void* d_ws, size_t ws_size,
                              hipStream_t stream) {
  const float* x   = (const float*)d_in[0];
  const float* cw  = (const float*)d_in[1];
  const float* gnw = (const float*)d_in[2];
  const float* gnb = (const float*)d_in[3];
  const float* emb = (const float*)d_in[4];
  float* out = (float*)d_out;
  char* ws = (char*)d_ws;
  float*     h      = (float*)(ws + OFF_H);
  double*    part   = (double*)(ws + OFF_PART);
  float*     esq    = (float*)(ws + OFF_ESQ);
  unsigned*  counts = (unsigned*)(ws + OFF_CNT);
  float*     loss   = (float*)(ws + OFF_LOSS);
  _Float16*  embH   = (_Float16*)(ws + OFF_EMBH);
  _Float16*  wH     = (_Float16*)(ws + OFF_WH);
  _Float16*  wL     = (_Float16*)(ws + OFF_WL);

  hipLaunchKernelGGL(k_emb,   dim3(57),   dim3(256), 0, stream,
                     emb, cw, embH, wH, wL, esq, counts, loss);
  hipLaunchKernelGGL(k_conv2, dim3(512),  dim3(256), 0, stream, x, wH, wL, h, part);
  hipLaunchKernelGGL(k_vq2,   dim3(1024), dim3(256), 0, stream,
                     h, part, gnw, gnb, embH, esq, emb, out, counts, loss);
  hipLaunchKernelGGL(k_final, dim3(1),    dim3(256), 0, stream, counts, loss, out);
}

// Round 13
// 98.133 us; speedup vs baseline: 1.0228x; 1.0228x over previous
//
#include <hip/hip_runtime.h>
#include <math.h>

// Problem constants
#define BB 16
#define TT 2048
#define CC 512
#define GG 2
#define DD 256      // C/G
#define VV 320
#define DT (DD*TT)
#define NOUT ((size_t)BB*TT*CC)

// Workspace layout (bytes)
#define OFF_H      0ULL
#define SZ_H       ((size_t)BB*GG*TT*DD*4)          // 67108864
#define OFF_PART   (OFF_H + SZ_H)
#define OFF_MUSIG  (OFF_PART + 4096ULL*2*8)
#define OFF_ESQ    (OFF_MUSIG + 32ULL*2*4)
#define OFF_CNT    (OFF_ESQ + (size_t)GG*VV*4)
#define OFF_LOSS   (OFF_CNT + (size_t)GG*VV*4)
#define OFF_EMBH   67180032ULL                       // G*8*4*320*8 halfs = 327680 B
#define OFF_WH     (OFF_EMBH + 327680ULL)            // G*8*4*256*8 halfs = 262144 B
#define OFF_WL     (OFF_WH + 262144ULL)

typedef _Float16 half8   __attribute__((ext_vector_type(8)));
typedef float    f32x4   __attribute__((ext_vector_type(4)));

#define MARGIN 2e-3f
#define CAP 16

#define GLOAD_LDS16(g, l) \
  __builtin_amdgcn_global_load_lds((const __attribute__((address_space(1))) void*)(g), \
                                   (__attribute__((address_space(3))) void*)(l), 16, 0, 0)

// blocks 0..39: esq + emb fp16-hi plane. block 40: init. blocks 41..56: W hi/lo planes.
__global__ __launch_bounds__(256) void k_emb(const float* __restrict__ emb,
                                             const float* __restrict__ w,
                                             _Float16* __restrict__ embHp,
                                             _Float16* __restrict__ wHp,
                                             _Float16* __restrict__ wLp,
                                             float* __restrict__ esq,
                                             unsigned* __restrict__ counts,
                                             float* __restrict__ loss) {
  int blk = blockIdx.x;
  int tid = threadIdx.x;
  if (blk == 40) {
    for (int i = tid; i < GG*VV; i += 256) counts[i] = 0u;
    if (tid == 0) *loss = 0.0f;
    return;
  }
  if (blk >= 41) {
    int wblk = blk - 41;
    int g = wblk >> 3, c = wblk & 7;
    int o = tid;
    const float* wrow = w + (size_t)(g*DD + o)*DD + (c << 5);
    #pragma unroll
    for (int hgrp = 0; hgrp < 4; ++hgrp) {
      float4 f1 = *(const float4*)(wrow + (hgrp << 2));
      float4 f2 = *(const float4*)(wrow + (hgrp << 2) + 16);
      float fv[8] = {f1.x, f1.y, f1.z, f1.w, f2.x, f2.y, f2.z, f2.w};
      half8 vh, vl;
      #pragma unroll
      for (int e = 0; e < 8; ++e) {
        _Float16 hh = (_Float16)fv[e];
        vh[e] = hh;
        vl[e] = (_Float16)(fv[e] - (float)hh);
      }
      size_t base = (((((size_t)(g*8 + c)) << 2) + hgrp) << 8) + o;
      *(half8*)(wHp + (base << 3)) = vh;
      *(half8*)(wLp + (base << 3)) = vl;
    }
    return;
  }
  int g = blk / 20;
  int v0 = (blk % 20) * 16;
  int vl = tid >> 4, dl = tid & 15;
  int v = v0 + vl;
  double sq = 0.0;
  #pragma unroll
  for (int k = 0; k < 16; k++) {
    int d = dl + (k << 4);
    float e = emb[((size_t)v*GG + g)*DD + d];
    sq += (double)e * (double)e;
  }
  #pragma unroll
  for (int m = 1; m < 16; m <<= 1) sq += __shfl_xor(sq, m);
  if (dl == 0) esq[g*VV + v] = (float)sq;

  const int hgrp = dl >> 2, jb = dl & 3;
  #pragma unroll
  for (int c = 0; c < 8; ++c) {
    int k0 = (c << 5) + (hgrp << 2) + jb;
    int k1 = k0 + 16;
    float e0 = emb[((size_t)v*GG + g)*DD + k0];
    float e1 = emb[((size_t)v*GG + g)*DD + k1];
    size_t base = (((size_t)(g*8 + c)*4 + hgrp)*320 + v)*8;
    embHp[base + jb]     = (_Float16)e0;
    embHp[base + jb + 4] = (_Float16)e1;
  }
}

// Conv GEMM, fp16-split 3-pass (bit-identical math): counted-vmcnt pipeline.
__global__ __launch_bounds__(256, 2) void k_conv2(const float* __restrict__ x,
                                                  const _Float16* __restrict__ wH,
                                                  const _Float16* __restrict__ wL,
                                                  float* __restrict__ h,
                                                  double* __restrict__ part) {
  __shared__ __align__(16) char BsC[65536];
  __shared__ double r1[4], r2[4];
  const int bid = blockIdx.x;         // 512
  const int bg = bid >> 4, tt = bid & 15;
  const int b = bg >> 1, g = bg & 1;
  const int tid = threadIdx.x;
  const int wv = tid >> 6, lane = tid & 63;
  const int l15 = tid & 15, lh = lane >> 4;
  const int t0w = (tt << 7) + (wv << 5);

  f32x4 acc[2][16];
  #pragma unroll
  for (int tf = 0; tf < 2; ++tf)
    #pragma unroll
    for (int vf = 0; vf < 16; ++vf) acc[tf][vf] = 0.0f;

  const char* WHg = (const char*)(wH + ((size_t)g << 16));
  const char* WLg = (const char*)(wL + ((size_t)g << 16));
  const float* xb0 = x + ((size_t)(b*TT + t0w + l15)*CC + g*DD + (lh << 2));
  const float* xb1 = xb0 + ((size_t)16)*CC;

  {
    const char* sH = WHg + wv*4096 + lane*16;
    const char* sL = WLg + wv*4096 + lane*16;
    char* dH = BsC + wv*4096;
    char* dL = BsC + 32768 + wv*4096;
    #pragma unroll
    for (int i = 0; i < 4; ++i) {
      GLOAD_LDS16(sH + i*1024, dH + i*1024);
      GLOAD_LDS16(sL + i*1024, dL + i*1024);
    }
  }
  float4 p00 = *(const float4*)(xb0);
  float4 p01 = *(const float4*)(xb0 + 16);
  float4 p10 = *(const float4*)(xb1);
  float4 p11 = *(const float4*)(xb1 + 16);

  int cur = 0;
  #pragma unroll 1
  for (int c = 0; c < 8; ++c) {
    if (c < 7) {
      const char* sH = WHg + (size_t)(c + 1)*16384 + wv*4096 + lane*16;
      const char* sL = WLg + (size_t)(c + 1)*16384 + wv*4096 + lane*16;
      char* dH = BsC + (cur ^ 1)*16384 + wv*4096;
      char* dL = BsC + 32768 + (cur ^ 1)*16384 + wv*4096;
      #pragma unroll
      for (int i = 0; i < 4; ++i) {
        GLOAD_LDS16(sH + i*1024, dH + i*1024);
        GLOAD_LDS16(sL + i*1024, dL + i*1024);
      }
      asm volatile("s_waitcnt vmcnt(12)" ::: "memory");
    } else {
      asm volatile("s_waitcnt vmcnt(4)" ::: "memory");
    }
    __builtin_amdgcn_s_barrier();

    float4 c00 = p00, c01 = p01, c10 = p10, c11 = p11;
    if (c < 7) {
      const int off = (c + 1) << 5;
      p00 = *(const float4*)(xb0 + off);
      p01 = *(const float4*)(xb0 + off + 16);
      p10 = *(const float4*)(xb1 + off);
      p11 = *(const float4*)(xb1 + off + 16);
    }
    half8 ah[2], al[2];
    {
      float fv0[8] = {c00.x, c00.y, c00.z, c00.w, c01.x, c01.y, c01.z, c01.w};
      float fv1[8] = {c10.x, c10.y, c10.z, c10.w, c11.x, c11.y, c11.z, c11.w};
      #pragma unroll
      for (int e = 0; e < 8; ++e) {
        _Float16 h0 = (_Float16)fv0[e];
        ah[0][e] = h0; al[0][e] = (_Float16)(fv0[e] - (float)h0);
        _Float16 h1 = (_Float16)fv1[e];
        ah[1][e] = h1; al[1][e] = (_Float16)(fv1[e] - (float)h1);
      }
    }
    const char* BH = BsC + cur*16384;
    const char* BL = BsC + 32768 + cur*16384;
    #pragma unroll
    for (int vf = 0; vf < 16; ++vf) {
      const int o = (vf << 4) + l15;
      const int bo = ((lh << 8) + o) << 4;
      half8 bh = *(const half8*)(BH + bo);
      half8 bl = *(const half8*)(BL + bo);
      #pragma unroll
      for (int tf = 0; tf < 2; ++tf) {
        acc[tf][vf] = __builtin_amdgcn_mfma_f32_16x16x32_f16(ah[tf], bh, acc[tf][vf], 0, 0, 0);
        acc[tf][vf] = __builtin_amdgcn_mfma_f32_16x16x32_f16(al[tf], bh, acc[tf][vf], 0, 0, 0);
        acc[tf][vf] = __builtin_amdgcn_mfma_f32_16x16x32_f16(ah[tf], bl, acc[tf][vf], 0, 0, 0);
      }
    }
    __builtin_amdgcn_s_barrier();
    cur ^= 1;
  }

  double s1 = 0.0, s2 = 0.0;
  {
    float* hb = h + (size_t)bg*TT*DD;
    #pragma unroll
    for (int tf = 0; tf < 2; ++tf) {
      #pragma unroll
      for (int reg = 0; reg < 4; ++reg) {
        const int t = t0w + (tf << 4) + (lh << 2) + reg;
        float* hrow = hb + (size_t)t*DD + l15;
        #pragma unroll
        for (int vf = 0; vf < 16; ++vf) {
          float v = acc[tf][vf][reg];
          hrow[vf << 4] = v;
          double dv = (double)v;
          s1 += dv; s2 += dv*dv;
        }
      }
    }
  }
  #pragma unroll
  for (int m = 32; m > 0; m >>= 1) { s1 += __shfl_down(s1, m); s2 += __shfl_down(s2, m); }
  if (lane == 0) { r1[wv] = s1; r2[wv] = s2; }
  __syncthreads();
  if (tid == 0) {
    part[(size_t)bid*2]     = r1[0] + r1[1] + r1[2] + r1[3];
    part[(size_t)bid*2 + 1] = r2[0] + r2[1] + r2[2] + r2[3];
  }
}

// MFMA VQ: 128 rows x 320 v per block (512 blocks, 2 blocks/CU — exact 1-round
// grid). LDS-staged B dbuf with counted vmcnt (depth-1 h prefetch), gn in LDS,
// inline mu/rs. Selection + exact double recheck semantics unchanged.
__global__ __launch_bounds__(256, 2) void k_vq2(const float* __restrict__ h,
                                                const double* __restrict__ part,
                                                const float* __restrict__ gn_w,
                                                const float* __restrict__ gn_b,
                                                const _Float16* __restrict__ embH,
                                                const float* __restrict__ esq,
                                                const float* __restrict__ emb,
                                                float* __restrict__ out,
                                                unsigned* __restrict__ counts,
                                                float* __restrict__ loss) {
  __shared__ __align__(16) char smem[43008];   // B dbuf 2x20480 | gnws 1K | gnbs 1K
  float*  esqs    = (float*)smem;                // overlay (after K-loop): 320 f
  int*    candcnt = (int*)(smem + 1280);         // 128
  int*    bestv   = (int*)(smem + 1792);         // 128
  int*    slowl   = (int*)(smem + 2304);         // 128
  int*    nslow   = (int*)(smem + 2816);
  float*  ze2s    = (float*)(smem + 2880);       // 128
  float*  ymins   = (float*)(smem + 3392);       // 128
  float*  lossrow = (float*)(smem + 3904);       // 128
  unsigned short* cand = (unsigned short*)(smem + 4416);  // [128][CAP] -> ends 8512
  float*  gnws    = (float*)(smem + 40960);      // 256 f (outside dbuf + overlay)
  float*  gnbs    = (float*)(smem + 41984);      // 256 f

  const int bid = blockIdx.x;        // 512 blocks
  const int bg  = bid >> 4;
  const int t0  = (bid & 15) << 7;
  const int b = bg >> 1, g = bg & 1;
  const int tid = threadIdx.x;
  const int lane = tid & 63, wv = tid >> 6;
  const int l15 = tid & 15, lh = lane >> 4;

  // mu/rs: redundant per-thread double sum over part (bit-identical to k_stats)
  float mu, rs;
  {
    double s1 = 0.0, s2 = 0.0;
    const double* pp = part + (size_t)bg*32;
    for (int r = 0; r < 16; r++) { s1 += pp[r*2]; s2 += pp[r*2 + 1]; }
    double mud = s1 / (double)DT;
    double var = s2 / (double)DT - mud*mud;
    double rsd = 1.0 / sqrt(var + 1e-5);
    mu = (float)mud;
    rs = (float)rsd;
  }

  const float* hb = h + ((size_t)bg*TT + t0)*DD;
  const char* gBH = (const char*)(embH + (size_t)(g*8)*10240);
  const float* gwp = gn_w + g*DD;
  const float* gbp = gn_b + g*DD;

  gnws[tid] = gwp[tid];
  gnbs[tid] = gbp[tid];
  __syncthreads();

  f32x4 acc[2][20];
  #pragma unroll
  for (int tf = 0; tf < 2; ++tf)
    #pragma unroll
    for (int vf = 0; vf < 20; ++vf) acc[tf][vf] = 0.0f;

  // wave wv owns rows [wv*32, wv*32+32): rowgroup tf0 = +l15, tf1 = +16+l15
  const float* hr0 = hb + (size_t)((wv << 5) + l15)*DD + (lh << 2);
  const float* hr1 = hr0 + ((size_t)16)*DD;

  // prologue: stage B chunk0 (5), then h chunk0 (4)
  {
    const char* sB = gBH + wv*5120 + lane*16;
    char* dB = smem + wv*5120;
    #pragma unroll
    for (int i = 0; i < 5; ++i) GLOAD_LDS16(sB + i*1024, dB + i*1024);
  }
  asm volatile("" ::: "memory");
  float4 a00 = *(const float4*)(hr0);
  float4 a01 = *(const float4*)(hr0 + 16);
  float4 a10 = *(const float4*)(hr1);
  float4 a11 = *(const float4*)(hr1 + 16);

  float ze2a0 = 0.0f, ze2a1 = 0.0f;
  #pragma unroll
  for (int c = 0; c < 8; ++c) {
    const int cu = c & 1;
    // issue: stage B chunk c+1 (5 loads), then h chunk c+1 (4 loads)
    if (c < 7) {
      const char* sB = gBH + (size_t)(c + 1)*20480 + wv*5120 + lane*16;
      char* dB = smem + (cu ^ 1)*20480 + wv*5120;
      #pragma unroll
      for (int i = 0; i < 5; ++i) GLOAD_LDS16(sB + i*1024, dB + i*1024);
    }
    asm volatile("" ::: "memory");
    float4 n00, n01, n10, n11;
    if (c < 7) {
      const int off = (c + 1) << 5;
      n00 = *(const float4*)(hr0 + off);
      n01 = *(const float4*)(hr0 + off + 16);
      n10 = *(const float4*)(hr1 + off);
      n11 = *(const float4*)(hr1 + off + 16);
    }
    // queue before wait: [s_c 5][h_c 4][s_{c+1} 5][h_{c+1} 4] -> drain s_c
    if (c < 7) { asm volatile("s_waitcnt vmcnt(13)" ::: "memory"); }
    else       { asm volatile("s_waitcnt vmcnt(4)"  ::: "memory"); }
    __builtin_amdgcn_s_barrier();

    const int c32 = c << 5;
    half8 ah[2];
    {
      float4 w1 = *(const float4*)(gnws + c32 + (lh << 2));
      float4 w2 = *(const float4*)(gnws + c32 + (lh << 2) + 16);
      float4 b1 = *(const float4*)(gnbs + c32 + (lh << 2));
      float4 b2 = *(const float4*)(gnbs + c32 + (lh << 2) + 16);
      float wv_[8] = {w1.x, w1.y, w1.z, w1.w, w2.x, w2.y, w2.z, w2.w};
      float bv_[8] = {b1.x, b1.y, b1.z, b1.w, b2.x, b2.y, b2.z, b2.w};
      float f0[8] = {a00.x, a00.y, a00.z, a00.w, a01.x, a01.y, a01.z, a01.w};
      float f1[8] = {a10.x, a10.y, a10.z, a10.w, a11.x, a11.y, a11.z, a11.w};
      #pragma unroll
      for (int e = 0; e < 8; ++e) {
        float z0 = __fmul_rn(__fsub_rn(f0[e], mu), rs);
        z0 = __fadd_rn(__fmul_rn(z0, wv_[e]), bv_[e]);
        ah[0][e] = (_Float16)z0;
        ze2a0 = fmaf(z0, z0, ze2a0);
        float z1 = __fmul_rn(__fsub_rn(f1[e], mu), rs);
        z1 = __fadd_rn(__fmul_rn(z1, wv_[e]), bv_[e]);
        ah[1][e] = (_Float16)z1;
        ze2a1 = fmaf(z1, z1, ze2a1);
      }
    }
    const char* BH = smem + cu*20480;
    #pragma unroll
    for (int vf = 0; vf < 20; ++vf) {
      const int v = (vf << 4) + l15;
      half8 bh = *(const half8*)(BH + ((lh*320 + v) << 4));
      acc[0][vf] = __builtin_amdgcn_mfma_f32_16x16x32_f16(ah[0], bh, acc[0][vf], 0, 0, 0);
      acc[1][vf] = __builtin_amdgcn_mfma_f32_16x16x32_f16(ah[1], bh, acc[1][vf], 0, 0, 0);
    }
    __builtin_amdgcn_s_barrier();
    if (c < 7) { a00 = n00; a01 = n01; a10 = n10; a11 = n11; }
  }
  __syncthreads();

  // ---- epilogue: overlay init + ze2 ----
  if (tid < 160) { esqs[tid] = esq[g*VV + tid]; esqs[tid + 160] = esq[g*VV + tid + 160]; }
  if (tid < 128) { candcnt[tid] = 0; bestv[tid] = -1; }
  if (tid == 0) *nslow = 0;
  {
    float s = ze2a0;
    s += __shfl_down(s, 32);
    s += __shfl_down(s, 16);
    if (lane < 16) ze2s[(wv << 5) + l15] = s;
    float t = ze2a1;
    t += __shfl_down(t, 32);
    t += __shfl_down(t, 16);
    if (lane < 16) ze2s[(wv << 5) + 16 + l15] = t;
  }
  __syncthreads();

  // selection: y = esq - 2c'; candidates within MARGIN of row min
  #pragma unroll
  for (int tf = 0; tf < 2; ++tf) {
    #pragma unroll
    for (int reg = 0; reg < 4; ++reg) {
      int row = (wv << 5) + (tf << 4) + (lh << 2) + reg;
      float y[20]; float mn = 3.4e38f;
      #pragma unroll
      for (int vf = 0; vf < 20; ++vf) {
        y[vf] = fmaf(-2.0f, acc[tf][vf][reg], esqs[(vf << 4) + l15]);
        mn = fminf(mn, y[vf]);
      }
      #pragma unroll
      for (int m = 1; m < 16; m <<= 1) mn = fminf(mn, __shfl_xor(mn, m));
      if (l15 == 0) ymins[row] = mn;
      float thr = mn + MARGIN;
      #pragma unroll
      for (int vf = 0; vf < 20; ++vf) {
        if (y[vf] <= thr) {
          int pos = atomicAdd(&candcnt[row], 1);
          if (pos < CAP) cand[row*CAP + pos] = (unsigned short)((vf << 4) + l15);
        }
      }
    }
  }
  __syncthreads();
  if (tid < 128) {
    int cnt = candcnt[tid];
    if (cnt == 1) {
      bestv[tid] = cand[tid*CAP];
      lossrow[tid] = ze2s[tid] + ymins[tid];
    } else {
      int p = atomicAdd(nslow, 1); slowl[p] = tid;
    }
  }
  __syncthreads();

  // slow path: wave-parallel double-precision recheck
  const int ns = *nslow;
  for (int i = wv; i < ns; i += 4) {
    const int row = slowl[i];
    float4 hx  = *(const float4*)(hb + (size_t)row*DD + (lane << 2));
    float4 gw4 = *(const float4*)(gwp + (lane << 2));
    float4 gb4 = *(const float4*)(gbp + (lane << 2));
    float hv[4] = {hx.x, hx.y, hx.z, hx.w};
    float gwv[4] = {gw4.x, gw4.y, gw4.z, gw4.w};
    float gbv[4] = {gb4.x, gb4.y, gb4.z, gb4.w};
    float zf[4];
    #pragma unroll
    for (int e = 0; e < 4; ++e) {
      float z = __fmul_rn(__fsub_rn(hv[e], mu), rs);
      zf[e] = __fadd_rn(__fmul_rn(z, gwv[e]), gbv[e]);
    }
    int cnt = candcnt[row];
    double bd = 1e300; int bvv = 0x7fffffff;
    if (cnt <= CAP) {
      for (int ci = 0; ci < cnt; ++ci) {
        int v = cand[row*CAP + ci];
        float4 ev = *(const float4*)(emb + ((size_t)v*GG + g)*DD + (lane << 2));
        float evv[4] = {ev.x, ev.y, ev.z, ev.w};
        double s = 0.0;
        #pragma unroll
        for (int e = 0; e < 4; ++e) {
          double df = (double)zf[e] - (double)evv[e];
          s += df*df;
        }
        #pragma unroll
        for (int m = 32; m > 0; m >>= 1) s += __shfl_down(s, m);
        s = __shfl(s, 0);
        if (s < bd || (s == bd && v < bvv)) { bd = s; bvv = v; }
      }
    } else {
      for (int v = 0; v < VV; ++v) {
        float4 ev = *(const float4*)(emb + ((size_t)v*GG + g)*DD + (lane << 2));
        float evv[4] = {ev.x, ev.y, ev.z, ev.w};
        double s = 0.0;
        #pragma unroll
        for (int e = 0; e < 4; ++e) {
          double df = (double)zf[e] - (double)evv[e];
          s += df*df;
        }
        #pragma unroll
        for (int m = 32; m > 0; m >>= 1) s += __shfl_down(s, m);
        s = __shfl(s, 0);
        if (s < bd) { bd = s; bvv = v; }
      }
    }
    if (lane == 0) { bestv[row] = bvv; lossrow[row] = (float)bd; }
  }
  __syncthreads();

  if (tid < 128) atomicAdd(&counts[g*VV + bestv[tid]], 1u);
  if (wv == 0) {
    float s = lossrow[lane] + lossrow[lane + 64];
    #pragma unroll
    for (int m = 32; m > 0; m >>= 1) s += __shfl_down(s, m);
    if (lane == 0) atomicAdd(loss, s);
  }

  // Phase 3: x_out = selected embedding, 8-row batches for ILP
  float* ob = out + (size_t)(b*TT + t0)*CC + g*DD + tid;
  #pragma unroll 1
  for (int r0 = 0; r0 < 128; r0 += 8) {
    int vv[8]; float ee[8];
    #pragma unroll
    for (int j = 0; j < 8; ++j) vv[j] = bestv[r0 + j];
    #pragma unroll
    for (int j = 0; j < 8; ++j) ee[j] = emb[((size_t)vv[j]*GG + g)*DD + tid];
    #pragma unroll
    for (int j = 0; j < 8; ++j) ob[(size_t)(r0 + j)*CC] = ee[j];
  }
}

__global__ __launch_bounds__(256) void k_final(const unsigned* __restrict__ counts,
                                               const float* __restrict__ loss,
                                               float* __restrict__ out) {
  __shared__ float sd[256];
  int tid = threadIdx.x;
  float perp = 0.0f;
  for (int g = 0; g < GG; g++) {
    float p1 = 0.0f;
    for (int v = tid; v < VV; v += 256) {
      float p = (float)counts[g*VV + v] / 32768.0f;
      p1 += p * logf(p + 1e-7f);
    }
    sd[tid] = p1;
    __syncthreads();
    for (int s = 128; s > 0; s >>= 1) {
      if (tid < s) sd[tid] += sd[tid + s];
      __syncthreads();
    }
    if (tid == 0) perp += expf(-sd[0]);
    __syncthreads();
  }
  if (tid == 0) {
    out[NOUT]     = 1.25f * (*loss) / (float)NOUT;
    out[NOUT + 1] = perp;
  }
}

extern "C" void kernel_launch(void* const* d_in, const int* in_sizes, int n_in,
                              void* d_out, int out_size, void* d_ws, size_t ws_size,
                              hipStream_t stream) {
  const float* x   = (const float*)d_in[0];
  const float* cw  = (const float*)d_in[1];
  const float* gnw = (const float*)d_in[2];
  const float* gnb = (const float*)d_in[3];
  const float* emb = (const float*)d_in[4];
  float* out = (float*)d_out;
  char* ws = (char*)d_ws;
  float*     h      = (float*)(ws + OFF_H);
  double*    part   = (double*)(ws + OFF_PART);
  float*     esq    = (float*)(ws + OFF_ESQ);
  unsigned*  counts = (unsigned*)(ws + OFF_CNT);
  float*     loss   = (float*)(ws + OFF_LOSS);
  _Float16*  embH   = (_Float16*)(ws + OFF_EMBH);
  _Float16*  wH     = (_Float16*)(ws + OFF_WH);
  _Float16*  wL     = (_Float16*)(ws + OFF_WL);

  hipLaunchKernelGGL(k_emb,   dim3(57),   dim3(256), 0, stream,
                     emb, cw, embH, wH, wL, esq, counts, loss);
  hipLaunchKernelGGL(k_conv2, dim3(512),  dim3(256), 0, stream, x, wH, wL, h, part);
  hipLaunchKernelGGL(k_vq2,   dim3(512),  dim3(256), 0, stream,
                     h, part, gnw, gnb, embH, esq, emb, out, counts, loss);
  hipLaunchKernelGGL(k_final, dim3(1),    dim3(256), 0, stream, counts, loss, out);
}